// Round 6
// baseline (177.396 us; speedup 1.0000x reference)
//
#include <hip/hip_runtime.h>
#include <hip/hip_bf16.h>
#include <cstdint>

// Problem constants
#define BATCH 2
#define SEQLEN 512
#define BL (BATCH*SEQLEN)       // 1024 rows
#define DMODEL 1024
#define DINNER 2048
#define NHEADS 32
#define HEADDIM 64
#define DSTATE 128
#define CONVDIM 2304            // DINNER + 2*DSTATE
#define DINPROJ 4384            // 2*DINNER + 2*DSTATE + NHEADS
#define NPROJPAD 4480           // DINPROJ padded to 128 multiple (DMA-safe N tail)
#define NCLS 48
#define QC 64                   // scan chunk length
#define NCH 8                   // chunks per sequence (SEQLEN/QC)

typedef short bf16x8 __attribute__((ext_vector_type(8)));
typedef float f32x4  __attribute__((ext_vector_type(4)));
typedef unsigned int u32;
typedef const __attribute__((address_space(1))) u32 gu32;
typedef __attribute__((address_space(3))) u32 lu32;

static __device__ __forceinline__ void gl16(const void* g, void* l) {
    // async global->LDS DMA, 16B/lane; LDS dest = wave-uniform base + lane*16
    __builtin_amdgcn_global_load_lds((gu32*)g, (lu32*)l, 16, 0, 0);
}

static __device__ __forceinline__ unsigned short f2bf(float f) {
    unsigned u = __float_as_uint(f);
    unsigned r = (u + 0x7FFFu + ((u >> 16) & 1u)) >> 16;
    return (unsigned short)r;
}
static __device__ __forceinline__ float bf2f(unsigned short u) {
    return __uint_as_float(((unsigned)u) << 16);
}

// ---------------- K0: merged prep: cvt_a | transpose W_in | cls prep ---------
// bid < 1024           : inputs fp32 -> bf16 (1024 elems/block)
// bid < 1024+4384      : W_in (1024x4384) -> Wt bf16 (4384x1024), 32x32 tiles
// else (240)           : out=bias broadcast (192) + W_cls^T bf16 (48)
__global__ __launch_bounds__(256) void k_prep(const float* __restrict__ in,
                                              unsigned short* __restrict__ abf,
                                              const float* __restrict__ W,
                                              unsigned short* __restrict__ Wt,
                                              const float* __restrict__ Wcls,
                                              const float* __restrict__ bcls,
                                              unsigned short* __restrict__ Wtc,
                                              float* __restrict__ out) {
    __shared__ float tile[32][33];
    int bid = blockIdx.x;
    int tid = threadIdx.x;
    if (bid < 1024) {
        int i = (bid * 256 + tid) * 4;
        float4 v = *(const float4*)(in + i);
        ushort4 o;
        o.x = f2bf(v.x); o.y = f2bf(v.y); o.z = f2bf(v.z); o.w = f2bf(v.w);
        *(ushort4*)(abf + i) = o;
    } else if (bid < 1024 + 4384) {
        int t = bid - 1024;
        int n0 = (t % 137) * 32;      // over 4384
        int k0 = (t / 137) * 32;      // over 1024
        int tx = tid & 31, ty = tid >> 5;
#pragma unroll
        for (int i = 0; i < 4; ++i) {
            int k = k0 + ty + i * 8;
            tile[ty + i * 8][tx] = W[(size_t)k * DINPROJ + n0 + tx];
        }
        __syncthreads();
#pragma unroll
        for (int i = 0; i < 4; ++i) {
            int n = n0 + ty + i * 8;
            Wt[(size_t)n * DMODEL + k0 + tx] = f2bf(tile[tx][ty + i * 8]);
        }
    } else {
        int b2 = bid - (1024 + 4384);
        if (b2 < 192) {
            int i = b2 * 256 + tid;
            out[i] = bcls[i % NCLS];
        } else {
            int n = b2 - 192;          // 0..47
            for (int k = tid; k < DINNER; k += 256)
                Wtc[(size_t)n * DINNER + k] = f2bf(Wcls[(size_t)k * NCLS + n]);
        }
    }
}

// ---------------- K1: zxbcdt = A(1024x1024) @ W(1024x4384) -> bf16 -----------
// BM=128, BN=64, BK=64 (two 32-halves), grid 70x8 = 560 blocks (load balance).
// 4 waves 2x2 over (M 2x64, N 2x32); 16 MFMA + 6 gl16 per wave per K-iter.
__global__ __launch_bounds__(256) void k_gemm_in(const unsigned short* __restrict__ A,
                                                 const unsigned short* __restrict__ Bt,
                                                 unsigned short* __restrict__ C) {
    __shared__ unsigned short As[2 * 4096];   // [half][128][32] unpadded (DMA layout)
    __shared__ unsigned short Bs[2 * 2048];   // [half][64][32]
    const int tid  = threadIdx.x;
    const int m0   = blockIdx.y * 128;
    const int n0   = blockIdx.x * 64;
    const int w    = tid >> 6;
    const int lane = tid & 63;
    const int wm   = w >> 1, wn = w & 1;
    const int fr   = lane & 15, fq = lane >> 4;
    const int srow = w * 16 + (lane >> 2);
    const int skg  = (lane & 3) * 8;
    const unsigned short* gA0 = A  + (size_t)(m0 + srow) * DMODEL + skg;
    const unsigned short* gA1 = gA0 + (size_t)64 * DMODEL;
    const unsigned short* gB0 = Bt + (size_t)(n0 + srow) * DMODEL + skg;

    f32x4 acc[4][2] = {};
    for (int k0 = 0; k0 < DMODEL; k0 += 64) {
        __syncthreads();
#pragma unroll
        for (int hh = 0; hh < 2; ++hh) {
            int kg = k0 + hh * 32;
            gl16(gA0 + kg, As + hh * 4096 + w * 512);
            gl16(gA1 + kg, As + hh * 4096 + 2048 + w * 512);
            gl16(gB0 + kg, Bs + hh * 2048 + w * 512);
        }
        __syncthreads();
#pragma unroll
        for (int hh = 0; hh < 2; ++hh) {
            bf16x8 af[4], bfr[2];
#pragma unroll
            for (int mt = 0; mt < 4; ++mt)
                af[mt] = *(const bf16x8*)(&As[hh * 4096 + (wm * 64 + mt * 16 + fr) * 32 + fq * 8]);
#pragma unroll
            for (int nt = 0; nt < 2; ++nt)
                bfr[nt] = *(const bf16x8*)(&Bs[hh * 2048 + (wn * 32 + nt * 16 + fr) * 32 + fq * 8]);
#pragma unroll
            for (int mt = 0; mt < 4; ++mt)
#pragma unroll
                for (int nt = 0; nt < 2; ++nt)
                    acc[mt][nt] = __builtin_amdgcn_mfma_f32_16x16x32_bf16(af[mt], bfr[nt], acc[mt][nt], 0, 0, 0);
        }
    }
#pragma unroll
    for (int mt = 0; mt < 4; ++mt) {
#pragma unroll
        for (int nt = 0; nt < 2; ++nt) {
            int col = n0 + wn * 32 + nt * 16 + fr;
            if (col < DINPROJ) {
#pragma unroll
                for (int r = 0; r < 4; ++r) {
                    int row = m0 + wm * 64 + mt * 16 + fq * 4 + r;
                    C[(size_t)row * DINPROJ + col] = f2bf(acc[mt][nt][r]);
                }
            }
        }
    }
}

// ---------------- K3a: chunked SSD w/ fused depthwise conv -------------------
// One WG (256 thr) per (b,h,chunk). Conv(x,B,C)+silu computed in-block from
// bf16 zx (rolling window); dt from zx dt-col; then 3 MFMA GEMMs as before.
__global__ __launch_bounds__(256) void k_chunk(const unsigned short* __restrict__ zx,
                                               const float* __restrict__ conv_w,
                                               const float* __restrict__ conv_b,
                                               const float* __restrict__ dt_bias,
                                               const float* __restrict__ A_log,
                                               const float* __restrict__ Dvec,
                                               float* __restrict__ yb,
                                               unsigned short* __restrict__ Sc_bf,
                                               float* __restrict__ lam_g,
                                               float* __restrict__ esc_g) {
    const int gid = blockIdx.x;           // 0..511
    const int cq = gid & 7;
    const int h = (gid >> 3) & 31;
    const int b = gid >> 8;
    const int row0 = b * SEQLEN + cq * QC;

    __shared__ float cumS[QC], wS[QC], dtS[QC];
    __shared__ unsigned short Xt[QC][72];        // [p][s] conv'd x
    __shared__ unsigned short Bs[QC][136];       // [s][n] conv'd B
    __shared__ unsigned short BtW[DSTATE][72];   // [n][s], weighted by w[s]
    __shared__ unsigned short Cs[QC][136];       // [t][n] conv'd C
    __shared__ unsigned short Gs[QC][72];        // [t][s], masked+decayed

    const int tid = threadIdx.x;
    // phase 0: dt + log-decay cumsum (wave 0)
    if (tid < 64) {
        float raw = bf2f(zx[(size_t)(row0 + tid) * DINPROJ + (DINNER + CONVDIM) + h]) + dt_bias[h];
        float dtv = (raw > 20.f) ? raw : log1pf(expf(raw));
        float nA = -expf(A_log[h]);
        float x = dtv * nA;
#pragma unroll
        for (int off = 1; off < 64; off <<= 1) {
            float v = __shfl_up(x, off, 64);
            if (tid >= off) x += v;
        }
        float cumTot = __shfl(x, 63, 64);
        cumS[tid] = x;
        dtS[tid] = dtv;
        wS[tid] = expf(cumTot - x) * dtv;
        esc_g[(size_t)gid * QC + tid] = expf(x);
        if (tid == 0) lam_g[gid] = expf(cumTot);
    }
    __syncthreads();

    // phase 1a: x-conv (64 ch x 64 rows), rolling window; Xt[ch][row]
    {
        int ch = tid & 63, rs = tid >> 6;
        const float* cwp = conv_w + (size_t)(h * 64 + ch) * 4;
        float w0 = cwp[0], w1 = cwp[1], w2 = cwp[2], w3 = cwp[3];
        float cb = conv_b[h * 64 + ch];
        int lb = cq * QC + rs * 16;
        const unsigned short* xcol = zx + (size_t)b * SEQLEN * DINPROJ + DINNER + h * 64 + ch;
        float xm3 = (lb >= 3) ? bf2f(xcol[(size_t)(lb - 3) * DINPROJ]) : 0.f;
        float xm2 = (lb >= 2) ? bf2f(xcol[(size_t)(lb - 2) * DINPROJ]) : 0.f;
        float xm1 = (lb >= 1) ? bf2f(xcol[(size_t)(lb - 1) * DINPROJ]) : 0.f;
#pragma unroll
        for (int r = 0; r < 16; ++r) {
            float xc = bf2f(xcol[(size_t)(lb + r) * DINPROJ]);
            float a = cb + w0 * xm3 + w1 * xm2 + w2 * xm1 + w3 * xc;
            float s = a / (1.f + expf(-a));
            Xt[ch][rs * 16 + r] = f2bf(s);
            xm3 = xm2; xm2 = xm1; xm1 = xc;
        }
    }
    // phase 1b: B/C-conv (256 ch x 64 rows), rolling window
    {
        int cc = tid;                       // zx col DINNER+2048+cc, conv ch 2048+cc
        const float* cwp = conv_w + (size_t)(2048 + cc) * 4;
        float w0 = cwp[0], w1 = cwp[1], w2 = cwp[2], w3 = cwp[3];
        float cb = conv_b[2048 + cc];
        int lb = cq * QC;
        const unsigned short* xcol = zx + (size_t)b * SEQLEN * DINPROJ + DINNER + 2048 + cc;
        float xm3 = (lb >= 3) ? bf2f(xcol[(size_t)(lb - 3) * DINPROJ]) : 0.f;
        float xm2 = (lb >= 2) ? bf2f(xcol[(size_t)(lb - 2) * DINPROJ]) : 0.f;
        float xm1 = (lb >= 1) ? bf2f(xcol[(size_t)(lb - 1) * DINPROJ]) : 0.f;
        for (int r = 0; r < QC; ++r) {
            float xc = bf2f(xcol[(size_t)(lb + r) * DINPROJ]);
            float a = cb + w0 * xm3 + w1 * xm2 + w2 * xm1 + w3 * xc;
            float s = a / (1.f + expf(-a));
            if (cc < 128) {
                Bs[r][cc] = f2bf(s);
                BtW[cc][r] = f2bf(s * wS[r]);
            } else {
                Cs[r][cc - 128] = f2bf(s);
            }
            xm3 = xm2; xm2 = xm1; xm1 = xc;
        }
    }
    __syncthreads();

    const int w = tid >> 6, lane = tid & 63;
    const int fr = lane & 15, fq = lane >> 4, fk = (lane >> 4) * 8;

    // GEMM1: G[t,s] = C[t]·B[s]
    f32x4 accG[4] = {};
#pragma unroll
    for (int kk = 0; kk < 4; ++kk) {
        bf16x8 a = *(const bf16x8*)(&Cs[w * 16 + fr][kk * 32 + fk]);
#pragma unroll
        for (int nt = 0; nt < 4; ++nt) {
            bf16x8 bb = *(const bf16x8*)(&Bs[nt * 16 + fr][kk * 32 + fk]);
            accG[nt] = __builtin_amdgcn_mfma_f32_16x16x32_bf16(a, bb, accG[nt], 0, 0, 0);
        }
    }
#pragma unroll
    for (int nt = 0; nt < 4; ++nt) {
        int s = nt * 16 + fr;
        float cs = cumS[s], dts = dtS[s];
#pragma unroll
        for (int r = 0; r < 4; ++r) {
            int t = w * 16 + fq * 4 + r;
            float val = (s <= t) ? accG[nt][r] * expf(cumS[t] - cs) * dts : 0.f;
            Gs[t][s] = f2bf(val);
        }
    }
    __syncthreads();

    // GEMM2: Y_intra = G' @ X
    f32x4 accY[4] = {};
#pragma unroll
    for (int kk = 0; kk < 2; ++kk) {
        bf16x8 a = *(const bf16x8*)(&Gs[w * 16 + fr][kk * 32 + fk]);
#pragma unroll
        for (int pt = 0; pt < 4; ++pt) {
            bf16x8 bb = *(const bf16x8*)(&Xt[pt * 16 + fr][kk * 32 + fk]);
            accY[pt] = __builtin_amdgcn_mfma_f32_16x16x32_bf16(a, bb, accY[pt], 0, 0, 0);
        }
    }
    // GEMM3: S_c[p,n] = X^T (w·B)
    f32x4 accS[8] = {};
#pragma unroll
    for (int kk = 0; kk < 2; ++kk) {
        bf16x8 a = *(const bf16x8*)(&Xt[w * 16 + fr][kk * 32 + fk]);
#pragma unroll
        for (int nt = 0; nt < 8; ++nt) {
            bf16x8 bb = *(const bf16x8*)(&BtW[nt * 16 + fr][kk * 32 + fk]);
            accS[nt] = __builtin_amdgcn_mfma_f32_16x16x32_bf16(a, bb, accS[nt], 0, 0, 0);
        }
    }
    float Dh = Dvec[h];
#pragma unroll
    for (int pt = 0; pt < 4; ++pt) {
        int p = pt * 16 + fr;
#pragma unroll
        for (int r = 0; r < 4; ++r) {
            int t = w * 16 + fq * 4 + r;
            float xv = bf2f(Xt[p][t]);
            yb[(size_t)(row0 + t) * DINNER + h * HEADDIM + p] = accY[pt][r] + Dh * xv;
        }
    }
    unsigned short* scp = Sc_bf + (size_t)gid * (HEADDIM * DSTATE);
#pragma unroll
    for (int nt = 0; nt < 8; ++nt) {
        int n = nt * 16 + fr;
#pragma unroll
        for (int r = 0; r < 4; ++r) {
            int p = w * 16 + fq * 4 + r;
            scp[p * DSTATE + n] = f2bf(accS[nt][r]);
        }
    }
}

// ---------------- K3b: inter-chunk state chain (256 WGs, serial over 8) ------
__global__ __launch_bounds__(256) void k_chain(const unsigned short* __restrict__ Sc_bf,
                                               const float* __restrict__ lam_g,
                                               unsigned short* __restrict__ Sin_bf) {
    int bh = blockIdx.x >> 2;      // 0..63
    int sl = blockIdx.x & 3;       // slice of the 8192-elem state
    int tid = threadIdx.x;
    float s[8];
#pragma unroll
    for (int i = 0; i < 8; ++i) s[i] = 0.f;
    for (int c = 0; c < NCH; ++c) {
        size_t base = (size_t)(bh * NCH + c) * (HEADDIM * DSTATE) + sl * 2048 + tid * 8;
        ushort4 o0, o1;
        o0.x = f2bf(s[0]); o0.y = f2bf(s[1]); o0.z = f2bf(s[2]); o0.w = f2bf(s[3]);
        o1.x = f2bf(s[4]); o1.y = f2bf(s[5]); o1.z = f2bf(s[6]); o1.w = f2bf(s[7]);
        *(ushort4*)(Sin_bf + base) = o0;
        *(ushort4*)(Sin_bf + base + 4) = o1;
        float lam = lam_g[bh * NCH + c];
        ushort4 v0 = *(const ushort4*)(Sc_bf + base);
        ushort4 v1 = *(const ushort4*)(Sc_bf + base + 4);
        s[0] = s[0] * lam + bf2f(v0.x);
        s[1] = s[1] * lam + bf2f(v0.y);
        s[2] = s[2] * lam + bf2f(v0.z);
        s[3] = s[3] * lam + bf2f(v0.w);
        s[4] = s[4] * lam + bf2f(v1.x);
        s[5] = s[5] * lam + bf2f(v1.y);
        s[6] = s[6] * lam + bf2f(v1.z);
        s[7] = s[7] * lam + bf2f(v1.w);
    }
}

// ---------------- K3c: cross-chunk term w/ fused C-conv ----------------------
// Y += exp(cum[t]) * conv_silu(C)_t · S_in
__global__ __launch_bounds__(256) void k_cross(const unsigned short* __restrict__ zx,
                                               const float* __restrict__ conv_w,
                                               const float* __restrict__ conv_b,
                                               const float* __restrict__ esc_g,
                                               const unsigned short* __restrict__ Sin_bf,
                                               float* __restrict__ yb) {
    const int gid = blockIdx.x;
    const int cq = gid & 7;
    const int h = (gid >> 3) & 31;
    const int b = gid >> 8;
    const int row0 = b * SEQLEN + cq * QC;
    __shared__ unsigned short Ct[QC][136];   // [t][n], conv'd C scaled by esc[t]
    __shared__ unsigned short Ss[QC][136];   // [p][n]
    __shared__ float escS[QC];
    const int tid = threadIdx.x;
    if (tid < 64) escS[tid] = esc_g[(size_t)gid * QC + tid];
    {
        int row = tid >> 2, g = tid & 3;
        const uint4* sp = (const uint4*)(Sin_bf + (size_t)gid * (HEADDIM * DSTATE));
#pragma unroll
        for (int i = 0; i < 4; ++i) {
            uint4 v = sp[row * 16 + g * 4 + i];
            *(uint4*)(&Ss[row][g * 32 + i * 8]) = v;
        }
    }
    __syncthreads();
    {
        int n = tid & 127, rs = tid >> 7;    // rows rs*32..+32
        const float* cwp = conv_w + (size_t)(2176 + n) * 4;
        float w0 = cwp[0], w1 = cwp[1], w2 = cwp[2], w3 = cwp[3];
        float cb = conv_b[2176 + n];
        int lb = cq * QC + rs * 32;
        const unsigned short* xcol = zx + (size_t)b * SEQLEN * DINPROJ + DINNER + 2176 + n;
        float xm3 = (lb >= 3) ? bf2f(xcol[(size_t)(lb - 3) * DINPROJ]) : 0.f;
        float xm2 = (lb >= 2) ? bf2f(xcol[(size_t)(lb - 2) * DINPROJ]) : 0.f;
        float xm1 = (lb >= 1) ? bf2f(xcol[(size_t)(lb - 1) * DINPROJ]) : 0.f;
        for (int r = 0; r < 32; ++r) {
            float xc = bf2f(xcol[(size_t)(lb + r) * DINPROJ]);
            float a = cb + w0 * xm3 + w1 * xm2 + w2 * xm1 + w3 * xc;
            float s = a / (1.f + expf(-a));
            Ct[rs * 32 + r][n] = f2bf(s * escS[rs * 32 + r]);
            xm3 = xm2; xm2 = xm1; xm1 = xc;
        }
    }
    __syncthreads();
    const int w = tid >> 6, lane = tid & 63;
    const int fr = lane & 15, fq = lane >> 4, fk = (lane >> 4) * 8;
    f32x4 acc[4] = {};
#pragma unroll
    for (int kk = 0; kk < 4; ++kk) {
        bf16x8 a = *(const bf16x8*)(&Ct[w * 16 + fr][kk * 32 + fk]);
#pragma unroll
        for (int pt = 0; pt < 4; ++pt) {
            bf16x8 bb = *(const bf16x8*)(&Ss[pt * 16 + fr][kk * 32 + fk]);
            acc[pt] = __builtin_amdgcn_mfma_f32_16x16x32_bf16(a, bb, acc[pt], 0, 0, 0);
        }
    }
#pragma unroll
    for (int pt = 0; pt < 4; ++pt) {
        int p = pt * 16 + fr;
#pragma unroll
        for (int r = 0; r < 4; ++r) {
            int t = w * 16 + fq * 4 + r;
            size_t yi = (size_t)(row0 + t) * DINNER + h * HEADDIM + p;
            yb[yi] += acc[pt][r];
        }
    }
}

// ---------------- K4a: gated RMSNorm -> bf16 G (z from bf16 zx) --------------
__global__ __launch_bounds__(256) void k_gate_norm(const unsigned short* __restrict__ zx,
                                                   const float* __restrict__ nw,
                                                   const float* __restrict__ y,
                                                   unsigned short* __restrict__ Gbf) {
    int row = blockIdx.x;
    int tid = threadIdx.x;
    const unsigned short* zrow = zx + (size_t)row * DINPROJ;   // z = cols [0,2048)
    const float* yr = y + (size_t)row * DINNER;
    float g[8];
    float ss = 0.f;
#pragma unroll
    for (int i = 0; i < 2; ++i) {
        int c = tid * 4 + i * 1024;
        float4 yv = *(const float4*)(yr + c);
        ushort4 zv = *(const ushort4*)(zrow + c);
        float zs[4] = {bf2f(zv.x), bf2f(zv.y), bf2f(zv.z), bf2f(zv.w)};
        float ys[4] = {yv.x, yv.y, yv.z, yv.w};
#pragma unroll
        for (int k = 0; k < 4; ++k) {
            float sil = zs[k] / (1.f + expf(-zs[k]));
            float gg = ys[k] * sil;
            g[i * 4 + k] = gg;
            ss += gg * gg;
        }
    }
#pragma unroll
    for (int off = 32; off >= 1; off >>= 1) ss += __shfl_xor(ss, off, 64);
    __shared__ float wsum[4];
    if ((tid & 63) == 0) wsum[tid >> 6] = ss;
    __syncthreads();
    float tot = wsum[0] + wsum[1] + wsum[2] + wsum[3];
    float scale = rsqrtf(tot / (float)DINNER + 1e-5f);
#pragma unroll
    for (int i = 0; i < 2; ++i) {
        int c = tid * 4 + i * 1024;
        float4 nv = *(const float4*)(nw + c);
        ushort4 o;
        o.x = f2bf(g[i * 4 + 0] * scale * nv.x);
        o.y = f2bf(g[i * 4 + 1] * scale * nv.y);
        o.z = f2bf(g[i * 4 + 2] * scale * nv.z);
        o.w = f2bf(g[i * 4 + 3] * scale * nv.w);
        *(ushort4*)(Gbf + (size_t)row * DINNER + c) = o;
    }
}

// ---------------- K4b: classifier GEMM (split-K, MFMA, atomicAdd) ------------
__global__ __launch_bounds__(256) void k_cls_mfma(const unsigned short* __restrict__ G,
                                                  const unsigned short* __restrict__ Wt,
                                                  float* __restrict__ out) {
    __shared__ unsigned short Gs[64][72];
    __shared__ unsigned short Ws[48][72];
    const int m0  = blockIdx.x * 64;
    const int k00 = blockIdx.y * 256;
    const int tid = threadIdx.x;
    const int w = tid >> 6, lane = tid & 63;
    const int fr = lane & 15, fq = lane >> 4, fk = fq * 8;
    f32x4 acc[3] = {};
    for (int ks = 0; ks < 4; ++ks) {
        int k0 = k00 + ks * 64;
        __syncthreads();
        {
            int row = tid >> 2, seg = (tid & 3) * 16;
            const unsigned short* gp = G + (size_t)(m0 + row) * DINNER + k0 + seg;
            *(uint4*)(&Gs[row][seg])     = *(const uint4*)(gp);
            *(uint4*)(&Gs[row][seg + 8]) = *(const uint4*)(gp + 8);
        }
        if (tid < 192) {
            int row = tid >> 2, seg = (tid & 3) * 16;
            const unsigned short* wp = Wt + (size_t)row * DINNER + k0 + seg;
            *(uint4*)(&Ws[row][seg])     = *(const uint4*)(wp);
            *(uint4*)(&Ws[row][seg + 8]) = *(const uint4*)(wp + 8);
        }
        __syncthreads();
#pragma unroll
        for (int kk = 0; kk < 2; ++kk) {
            bf16x8 a = *(const bf16x8*)(&Gs[w * 16 + fr][kk * 32 + fk]);
#pragma unroll
            for (int nt = 0; nt < 3; ++nt) {
                bf16x8 bb = *(const bf16x8*)(&Ws[nt * 16 + fr][kk * 32 + fk]);
                acc[nt] = __builtin_amdgcn_mfma_f32_16x16x32_bf16(a, bb, acc[nt], 0, 0, 0);
            }
        }
    }
#pragma unroll
    for (int nt = 0; nt < 3; ++nt) {
        int col = nt * 16 + fr;
#pragma unroll
        for (int r = 0; r < 4; ++r) {
            int row = m0 + w * 16 + fq * 4 + r;
            atomicAdd(&out[(size_t)row * NCLS + col], acc[nt][r]);
        }
    }
}

// ---------------- launch -----------------------------------------------------
extern "C" void kernel_launch(void* const* d_in, const int* in_sizes, int n_in,
                              void* d_out, int out_size, void* d_ws, size_t ws_size,
                              hipStream_t stream) {
    const float* inputs  = (const float*)d_in[0];
    const float* W_in    = (const float*)d_in[1];
    const float* conv_w  = (const float*)d_in[2];
    const float* conv_b  = (const float*)d_in[3];
    const float* dt_bias = (const float*)d_in[4];
    const float* A_log   = (const float*)d_in[5];
    const float* Dvec    = (const float*)d_in[6];
    const float* norm_w  = (const float*)d_in[7];
    // d_in[8] = W_out (unused by reference output)
    const float* W_cls   = (const float*)d_in[9];
    const float* b_cls   = (const float*)d_in[10];
    float* out = (float*)d_out;

    // workspace layout (~45 MB)
    float* ws = (float*)d_ws;
    unsigned short* zxb = (unsigned short*)ws;                   // BL*4384 bf16
    float* yb    = ws + (size_t)BL * DINPROJ / 2;                // BL*2048 fp32
    float* lam_g = yb + (size_t)BL * DINNER;                     // 512
    float* esc_g = lam_g + 512;                                  // 512*64
    unsigned short* Sc_bf  = (unsigned short*)(esc_g + 512 * QC);          // 512*8192 bf16
    unsigned short* Sin_bf = Sc_bf + (size_t)512 * HEADDIM * DSTATE;       // 512*8192 bf16
    unsigned short* abf    = Sin_bf + (size_t)512 * HEADDIM * DSTATE;      // BL*1024
    unsigned short* wtbf   = abf + (size_t)BL * DMODEL;                    // 4480*1024 (padded)
    unsigned short* wclsbf = wtbf + (size_t)NPROJPAD * DMODEL;             // 48*2048
    unsigned short* Gbf    = Sc_bf;   // alias: Sc_bf dead after k_chain

    k_prep<<<dim3(1024 + 4384 + 240), dim3(256), 0, stream>>>(inputs, abf, W_in, wtbf,
                                                              W_cls, b_cls, wclsbf, out);
    k_gemm_in<<<dim3(NPROJPAD / 64, BL / 128), dim3(256), 0, stream>>>(abf, wtbf, zxb);
    k_chunk<<<dim3(BATCH * NHEADS * NCH), dim3(256), 0, stream>>>(zxb, conv_w, conv_b,
                                                                  dt_bias, A_log, Dvec,
                                                                  yb, Sc_bf, lam_g, esc_g);
    k_chain<<<dim3(BATCH * NHEADS * 4), dim3(256), 0, stream>>>(Sc_bf, lam_g, Sin_bf);
    k_cross<<<dim3(BATCH * NHEADS * NCH), dim3(256), 0, stream>>>(zxb, conv_w, conv_b,
                                                                  esc_g, Sin_bf, yb);
    k_gate_norm<<<dim3(BL), dim3(256), 0, stream>>>(zxb, norm_w, yb, Gbf);
    k_cls_mfma<<<dim3(BL / 64, 8), dim3(256), 0, stream>>>(Gbf, wclsbf, out);
}

// Round 7
// 174.032 us; speedup vs baseline: 1.0193x; 1.0193x over previous
//
#include <hip/hip_runtime.h>
#include <hip/hip_bf16.h>
#include <cstdint>

// Problem constants
#define BATCH 2
#define SEQLEN 512
#define BL (BATCH*SEQLEN)       // 1024 rows
#define DMODEL 1024
#define DINNER 2048
#define NHEADS 32
#define HEADDIM 64
#define DSTATE 128
#define CONVDIM 2304            // DINNER + 2*DSTATE
#define DINPROJ 4384            // 2*DINNER + 2*DSTATE + NHEADS
#define NPROJPAD 4480           // DINPROJ padded to 128 multiple (DMA-safe N tail)
#define NCLS 48
#define QC 64                   // scan chunk length
#define NCH 8                   // chunks per sequence (SEQLEN/QC)

typedef short bf16x8 __attribute__((ext_vector_type(8)));
typedef float f32x4  __attribute__((ext_vector_type(4)));
typedef unsigned int u32;
typedef const __attribute__((address_space(1))) u32 gu32;
typedef __attribute__((address_space(3))) u32 lu32;

static __device__ __forceinline__ void gl16(const void* g, void* l) {
    // async global->LDS DMA, 16B/lane; LDS dest = wave-uniform base + lane*16
    __builtin_amdgcn_global_load_lds((gu32*)g, (lu32*)l, 16, 0, 0);
}

static __device__ __forceinline__ unsigned short f2bf(float f) {
    unsigned u = __float_as_uint(f);
    unsigned r = (u + 0x7FFFu + ((u >> 16) & 1u)) >> 16;
    return (unsigned short)r;
}
static __device__ __forceinline__ float bf2f(unsigned short u) {
    return __uint_as_float(((unsigned)u) << 16);
}

// ---------------- K0: merged prep: cvt_a | transpose W_in | cls W^T ----------
__global__ __launch_bounds__(256) void k_prep(const float* __restrict__ in,
                                              unsigned short* __restrict__ abf,
                                              const float* __restrict__ W,
                                              unsigned short* __restrict__ Wt,
                                              const float* __restrict__ Wcls,
                                              unsigned short* __restrict__ Wtc) {
    __shared__ float tile[32][33];
    int bid = blockIdx.x;
    int tid = threadIdx.x;
    if (bid < 1024) {
        int i = (bid * 256 + tid) * 4;
        float4 v = *(const float4*)(in + i);
        ushort4 o;
        o.x = f2bf(v.x); o.y = f2bf(v.y); o.z = f2bf(v.z); o.w = f2bf(v.w);
        *(ushort4*)(abf + i) = o;
    } else if (bid < 1024 + 4384) {
        int t = bid - 1024;
        int n0 = (t % 137) * 32;      // over 4384
        int k0 = (t / 137) * 32;      // over 1024
        int tx = tid & 31, ty = tid >> 5;
#pragma unroll
        for (int i = 0; i < 4; ++i) {
            int k = k0 + ty + i * 8;
            tile[ty + i * 8][tx] = W[(size_t)k * DINPROJ + n0 + tx];
        }
        __syncthreads();
#pragma unroll
        for (int i = 0; i < 4; ++i) {
            int n = n0 + ty + i * 8;
            Wt[(size_t)n * DMODEL + k0 + tx] = f2bf(tile[tx][ty + i * 8]);
        }
    } else {
        int n = bid - (1024 + 4384);   // 0..47
        for (int k = tid; k < DINNER; k += 256)
            Wtc[(size_t)n * DINNER + k] = f2bf(Wcls[(size_t)k * NCLS + n]);
    }
}

// ---------------- K1: zxbcdt = A(1024x1024) @ W(1024x4384) -> bf16 -----------
// BM=128, BN=128, BK=64 (two 32-halves); 4 waves 2x2; 32 MFMA + 8 gl16/wave/iter
__global__ __launch_bounds__(256) void k_gemm_in(const unsigned short* __restrict__ A,
                                                 const unsigned short* __restrict__ Bt,
                                                 unsigned short* __restrict__ C) {
    __shared__ unsigned short As[2 * 4096];   // [half][128][32] unpadded (DMA layout)
    __shared__ unsigned short Bs[2 * 4096];
    const int tid  = threadIdx.x;
    const int m0   = blockIdx.y * 128;
    const int n0   = blockIdx.x * 128;
    const int w    = tid >> 6;
    const int lane = tid & 63;
    const int wm   = w >> 1, wn = w & 1;
    const int fr   = lane & 15, fq = lane >> 4;
    const int srow = w * 16 + (lane >> 2);
    const int skg  = (lane & 3) * 8;
    const unsigned short* gA0 = A  + (size_t)(m0 + srow) * DMODEL + skg;
    const unsigned short* gA1 = gA0 + (size_t)64 * DMODEL;
    const unsigned short* gB0 = Bt + (size_t)(n0 + srow) * DMODEL + skg;
    const unsigned short* gB1 = gB0 + (size_t)64 * DMODEL;

    f32x4 acc[4][4] = {};
    for (int k0 = 0; k0 < DMODEL; k0 += 64) {
        __syncthreads();
#pragma unroll
        for (int hh = 0; hh < 2; ++hh) {
            int kg = k0 + hh * 32;
            gl16(gA0 + kg, As + hh * 4096 + w * 512);
            gl16(gA1 + kg, As + hh * 4096 + 2048 + w * 512);
            gl16(gB0 + kg, Bs + hh * 4096 + w * 512);
            gl16(gB1 + kg, Bs + hh * 4096 + 2048 + w * 512);
        }
        __syncthreads();
#pragma unroll
        for (int hh = 0; hh < 2; ++hh) {
            bf16x8 af[4], bfr[4];
#pragma unroll
            for (int mt = 0; mt < 4; ++mt)
                af[mt] = *(const bf16x8*)(&As[hh * 4096 + (wm * 64 + mt * 16 + fr) * 32 + fq * 8]);
#pragma unroll
            for (int nt = 0; nt < 4; ++nt)
                bfr[nt] = *(const bf16x8*)(&Bs[hh * 4096 + (wn * 64 + nt * 16 + fr) * 32 + fq * 8]);
#pragma unroll
            for (int mt = 0; mt < 4; ++mt)
#pragma unroll
                for (int nt = 0; nt < 4; ++nt)
                    acc[mt][nt] = __builtin_amdgcn_mfma_f32_16x16x32_bf16(af[mt], bfr[nt], acc[mt][nt], 0, 0, 0);
        }
    }
#pragma unroll
    for (int mt = 0; mt < 4; ++mt) {
#pragma unroll
        for (int nt = 0; nt < 4; ++nt) {
            int col = n0 + wn * 64 + nt * 16 + fr;
            if (col < DINPROJ) {
#pragma unroll
                for (int r = 0; r < 4; ++r) {
                    int row = m0 + wm * 64 + mt * 16 + fq * 4 + r;
                    C[(size_t)row * DINPROJ + col] = f2bf(acc[mt][nt][r]);
                }
            }
        }
    }
}

// ---------------- K2: causal depthwise conv + silu, and dt (bf16 zx) ---------
__global__ __launch_bounds__(256) void k_conv_dt(const unsigned short* __restrict__ zx,
                                                 const float* __restrict__ conv_w,
                                                 const float* __restrict__ conv_b,
                                                 const float* __restrict__ dt_bias,
                                                 float* __restrict__ xbc,
                                                 float* __restrict__ dtb) {
    int row = blockIdx.y;                 // b*512 + l
    int c   = blockIdx.x * 256 + threadIdx.x;
    int b = row >> 9, l = row & 511;
    if (c < CONVDIM) {
        float acc = conv_b[c];
#pragma unroll
        for (int j = 0; j < 4; ++j) {
            int ls = l - 3 + j;
            float v = (ls >= 0) ? bf2f(zx[((size_t)(b * SEQLEN + ls)) * DINPROJ + DINNER + c]) : 0.f;
            acc += v * conv_w[c * 4 + j];
        }
        float s = acc / (1.f + expf(-acc));
        xbc[(size_t)row * CONVDIM + c] = s;
    } else if (c < CONVDIM + NHEADS) {
        int h = c - CONVDIM;
        float raw = bf2f(zx[(size_t)row * DINPROJ + (DINNER + CONVDIM) + h]) + dt_bias[h];
        float dt = (raw > 20.f) ? raw : log1pf(expf(raw));
        dtb[row * NHEADS + h] = dt;
    }
}

// ---------------- K3a: chunked SSD, intra-chunk (Y_intra bf16 + Sc bf16) -----
__global__ __launch_bounds__(256) void k_chunk(const float* __restrict__ xbc,
                                               const float* __restrict__ dtb,
                                               const float* __restrict__ A_log,
                                               const float* __restrict__ Dvec,
                                               unsigned short* __restrict__ yb,
                                               unsigned short* __restrict__ Sc_bf,
                                               float* __restrict__ lam_g,
                                               float* __restrict__ esc_g) {
    const int gid = blockIdx.x;           // 0..511
    const int cq = gid & 7;
    const int h = (gid >> 3) & 31;
    const int b = gid >> 8;
    const int row0 = b * SEQLEN + cq * QC;

    __shared__ float cumS[QC], wS[QC], dtS[QC];
    __shared__ unsigned short Xt[QC][72];        // [p][s]
    __shared__ unsigned short Bs[QC][136];       // [s][n]
    __shared__ unsigned short BtW[DSTATE][72];   // [n][s], weighted by w[s]
    __shared__ unsigned short Cs[QC][136];       // [t][n]
    __shared__ unsigned short Gs[QC][72];        // [t][s], masked+decayed

    const int tid = threadIdx.x;
    if (tid < 64) {
        float dtv = dtb[(size_t)(row0 + tid) * NHEADS + h];
        float nA = -expf(A_log[h]);
        float x = dtv * nA;
#pragma unroll
        for (int off = 1; off < 64; off <<= 1) {
            float v = __shfl_up(x, off, 64);
            if (tid >= off) x += v;
        }
        float cumTot = __shfl(x, 63, 64);
        cumS[tid] = x;
        dtS[tid] = dtv;
        wS[tid] = expf(cumTot - x) * dtv;
        esc_g[(size_t)gid * QC + tid] = expf(x);
        if (tid == 0) lam_g[gid] = expf(cumTot);
    }
    __syncthreads();

    {
        int row = tid >> 2;       // s / t index 0..63
        int g = tid & 3;
        const float* rp = xbc + (size_t)(row0 + row) * CONVDIM;
        float wrow = wS[row];
#pragma unroll
        for (int i = 0; i < 4; ++i) {
            float4 v = *(const float4*)(rp + h * HEADDIM + g * 16 + i * 4);
            int p = g * 16 + i * 4;
            Xt[p + 0][row] = f2bf(v.x);
            Xt[p + 1][row] = f2bf(v.y);
            Xt[p + 2][row] = f2bf(v.z);
            Xt[p + 3][row] = f2bf(v.w);
        }
#pragma unroll
        for (int i = 0; i < 8; ++i) {
            int n = g * 32 + i * 4;
            float4 v = *(const float4*)(rp + DINNER + n);
            ushort4 u;
            u.x = f2bf(v.x); u.y = f2bf(v.y); u.z = f2bf(v.z); u.w = f2bf(v.w);
            *(ushort4*)(&Bs[row][n]) = u;
            BtW[n + 0][row] = f2bf(v.x * wrow);
            BtW[n + 1][row] = f2bf(v.y * wrow);
            BtW[n + 2][row] = f2bf(v.z * wrow);
            BtW[n + 3][row] = f2bf(v.w * wrow);
        }
#pragma unroll
        for (int i = 0; i < 8; ++i) {
            int n = g * 32 + i * 4;
            float4 v = *(const float4*)(rp + DINNER + DSTATE + n);
            ushort4 u;
            u.x = f2bf(v.x); u.y = f2bf(v.y); u.z = f2bf(v.z); u.w = f2bf(v.w);
            *(ushort4*)(&Cs[row][n]) = u;
        }
    }
    __syncthreads();

    const int w = tid >> 6, lane = tid & 63;
    const int fr = lane & 15, fq = lane >> 4, fk = (lane >> 4) * 8;

    f32x4 accG[4] = {};
#pragma unroll
    for (int kk = 0; kk < 4; ++kk) {
        bf16x8 a = *(const bf16x8*)(&Cs[w * 16 + fr][kk * 32 + fk]);
#pragma unroll
        for (int nt = 0; nt < 4; ++nt) {
            bf16x8 bb = *(const bf16x8*)(&Bs[nt * 16 + fr][kk * 32 + fk]);
            accG[nt] = __builtin_amdgcn_mfma_f32_16x16x32_bf16(a, bb, accG[nt], 0, 0, 0);
        }
    }
#pragma unroll
    for (int nt = 0; nt < 4; ++nt) {
        int s = nt * 16 + fr;
        float cs = cumS[s], dts = dtS[s];
#pragma unroll
        for (int r = 0; r < 4; ++r) {
            int t = w * 16 + fq * 4 + r;
            float val = (s <= t) ? accG[nt][r] * expf(cumS[t] - cs) * dts : 0.f;
            Gs[t][s] = f2bf(val);
        }
    }
    __syncthreads();

    f32x4 accY[4] = {};
#pragma unroll
    for (int kk = 0; kk < 2; ++kk) {
        bf16x8 a = *(const bf16x8*)(&Gs[w * 16 + fr][kk * 32 + fk]);
#pragma unroll
        for (int pt = 0; pt < 4; ++pt) {
            bf16x8 bb = *(const bf16x8*)(&Xt[pt * 16 + fr][kk * 32 + fk]);
            accY[pt] = __builtin_amdgcn_mfma_f32_16x16x32_bf16(a, bb, accY[pt], 0, 0, 0);
        }
    }
    f32x4 accS[8] = {};
#pragma unroll
    for (int kk = 0; kk < 2; ++kk) {
        bf16x8 a = *(const bf16x8*)(&Xt[w * 16 + fr][kk * 32 + fk]);
#pragma unroll
        for (int nt = 0; nt < 8; ++nt) {
            bf16x8 bb = *(const bf16x8*)(&BtW[nt * 16 + fr][kk * 32 + fk]);
            accS[nt] = __builtin_amdgcn_mfma_f32_16x16x32_bf16(a, bb, accS[nt], 0, 0, 0);
        }
    }
    float Dh = Dvec[h];
#pragma unroll
    for (int pt = 0; pt < 4; ++pt) {
        int p = pt * 16 + fr;
#pragma unroll
        for (int r = 0; r < 4; ++r) {
            int t = w * 16 + fq * 4 + r;
            float xv = xbc[(size_t)(row0 + t) * CONVDIM + h * HEADDIM + p];
            yb[(size_t)(row0 + t) * DINNER + h * HEADDIM + p] = f2bf(accY[pt][r] + Dh * xv);
        }
    }
    unsigned short* scp = Sc_bf + (size_t)gid * (HEADDIM * DSTATE);
#pragma unroll
    for (int nt = 0; nt < 8; ++nt) {
        int n = nt * 16 + fr;
#pragma unroll
        for (int r = 0; r < 4; ++r) {
            int p = w * 16 + fq * 4 + r;
            scp[p * DSTATE + n] = f2bf(accS[nt][r]);
        }
    }
}

// ---------------- K3b: inter-chunk state chain (256 WGs, serial over 8) ------
__global__ __launch_bounds__(256) void k_chain(const unsigned short* __restrict__ Sc_bf,
                                               const float* __restrict__ lam_g,
                                               unsigned short* __restrict__ Sin_bf) {
    int bh = blockIdx.x >> 2;      // 0..63
    int sl = blockIdx.x & 3;       // slice of the 8192-elem state
    int tid = threadIdx.x;
    float s[8];
#pragma unroll
    for (int i = 0; i < 8; ++i) s[i] = 0.f;
    for (int c = 0; c < NCH; ++c) {
        size_t base = (size_t)(bh * NCH + c) * (HEADDIM * DSTATE) + sl * 2048 + tid * 8;
        ushort4 o0, o1;
        o0.x = f2bf(s[0]); o0.y = f2bf(s[1]); o0.z = f2bf(s[2]); o0.w = f2bf(s[3]);
        o1.x = f2bf(s[4]); o1.y = f2bf(s[5]); o1.z = f2bf(s[6]); o1.w = f2bf(s[7]);
        *(ushort4*)(Sin_bf + base) = o0;
        *(ushort4*)(Sin_bf + base + 4) = o1;
        float lam = lam_g[bh * NCH + c];
        ushort4 v0 = *(const ushort4*)(Sc_bf + base);
        ushort4 v1 = *(const ushort4*)(Sc_bf + base + 4);
        s[0] = s[0] * lam + bf2f(v0.x);
        s[1] = s[1] * lam + bf2f(v0.y);
        s[2] = s[2] * lam + bf2f(v0.z);
        s[3] = s[3] * lam + bf2f(v0.w);
        s[4] = s[4] * lam + bf2f(v1.x);
        s[5] = s[5] * lam + bf2f(v1.y);
        s[6] = s[6] * lam + bf2f(v1.z);
        s[7] = s[7] * lam + bf2f(v1.w);
    }
}

// ---------------- K3c: cross-chunk: Y += exp(cum[t]) * C_t · S_in (bf16 yb) --
__global__ __launch_bounds__(256) void k_cross(const float* __restrict__ xbc,
                                               const float* __restrict__ esc_g,
                                               const unsigned short* __restrict__ Sin_bf,
                                               unsigned short* __restrict__ yb) {
    const int gid = blockIdx.x;
    const int cq = gid & 7;
    const int h = (gid >> 3) & 31;
    const int b = gid >> 8;
    const int row0 = b * SEQLEN + cq * QC;
    __shared__ unsigned short Ct[QC][136];   // [t][n], scaled by esc[t]
    __shared__ unsigned short Ss[QC][136];   // [p][n]
    const int tid = threadIdx.x;
    {
        int row = tid >> 2, g = tid & 3;
        const float* rp = xbc + (size_t)(row0 + row) * CONVDIM + DINNER + DSTATE;
        float esc = esc_g[(size_t)gid * QC + row];
#pragma unroll
        for (int i = 0; i < 8; ++i) {
            int n = g * 32 + i * 4;
            float4 v = *(const float4*)(rp + n);
            ushort4 u;
            u.x = f2bf(v.x * esc); u.y = f2bf(v.y * esc);
            u.z = f2bf(v.z * esc); u.w = f2bf(v.w * esc);
            *(ushort4*)(&Ct[row][n]) = u;
        }
        const uint4* sp = (const uint4*)(Sin_bf + (size_t)gid * (HEADDIM * DSTATE));
#pragma unroll
        for (int i = 0; i < 4; ++i) {
            uint4 v = sp[row * 16 + g * 4 + i];
            *(uint4*)(&Ss[row][g * 32 + i * 8]) = v;
        }
    }
    __syncthreads();
    const int w = tid >> 6, lane = tid & 63;
    const int fr = lane & 15, fq = lane >> 4, fk = (lane >> 4) * 8;
    f32x4 acc[4] = {};
#pragma unroll
    for (int kk = 0; kk < 4; ++kk) {
        bf16x8 a = *(const bf16x8*)(&Ct[w * 16 + fr][kk * 32 + fk]);
#pragma unroll
        for (int pt = 0; pt < 4; ++pt) {
            bf16x8 bb = *(const bf16x8*)(&Ss[pt * 16 + fr][kk * 32 + fk]);
            acc[pt] = __builtin_amdgcn_mfma_f32_16x16x32_bf16(a, bb, acc[pt], 0, 0, 0);
        }
    }
    // disjoint (b,h,chunk) tiles -> plain RMW on bf16 yb is race-free
#pragma unroll
    for (int pt = 0; pt < 4; ++pt) {
        int p = pt * 16 + fr;
#pragma unroll
        for (int r = 0; r < 4; ++r) {
            int t = w * 16 + fq * 4 + r;
            size_t yi = (size_t)(row0 + t) * DINNER + h * HEADDIM + p;
            yb[yi] = f2bf(bf2f(yb[yi]) + acc[pt][r]);
        }
    }
}

// ---------------- K4: fused gated RMSNorm + classifier -----------------------
// 64 WGs x 256 thr; WG owns 16 rows. Phase A: g=y*silu(z) -> LDS (+ rowsum).
// Rescale LDS by scale[row]*norm_w[k]. Phase B: 16x48x2048 MFMA, K split
// across 4 waves, cross-wave LDS reduce, out = acc + bias.
__global__ __launch_bounds__(256) void k_gn_cls(const unsigned short* __restrict__ zx,
                                                const unsigned short* __restrict__ yb,
                                                const float* __restrict__ nw,
                                                const unsigned short* __restrict__ Wt,
                                                const float* __restrict__ bcls,
                                                float* __restrict__ out) {
    __shared__ unsigned short Gs[16][2048];
    __shared__ float scaleS[16];
    __shared__ float Rs[3][4][256];
    const int m0 = blockIdx.x * 16;
    const int tid = threadIdx.x;
    const int w = tid >> 6, lane = tid & 63;

    // Phase A: wave w -> rows w*4 .. w*4+4
#pragma unroll
    for (int i = 0; i < 4; ++i) {
        int rl = w * 4 + i;
        int row = m0 + rl;
        const unsigned short* yr = yb + (size_t)row * DINNER;
        const unsigned short* zr = zx + (size_t)row * DINPROJ;
        float gv[32];
        float ss = 0.f;
#pragma unroll
        for (int i2 = 0; i2 < 4; ++i2) {
            int k = i2 * 512 + lane * 8;
            ushort4 ya = *(const ushort4*)(yr + k);
            ushort4 ybq = *(const ushort4*)(yr + k + 4);
            ushort4 za = *(const ushort4*)(zr + k);
            ushort4 zbq = *(const ushort4*)(zr + k + 4);
            float ys[8] = {bf2f(ya.x), bf2f(ya.y), bf2f(ya.z), bf2f(ya.w),
                           bf2f(ybq.x), bf2f(ybq.y), bf2f(ybq.z), bf2f(ybq.w)};
            float zs[8] = {bf2f(za.x), bf2f(za.y), bf2f(za.z), bf2f(za.w),
                           bf2f(zbq.x), bf2f(zbq.y), bf2f(zbq.z), bf2f(zbq.w)};
#pragma unroll
            for (int j = 0; j < 8; ++j) {
                float sil = zs[j] / (1.f + expf(-zs[j]));
                float gg = ys[j] * sil;
                gv[i2 * 8 + j] = gg;
                ss += gg * gg;
            }
        }
#pragma unroll
        for (int off = 32; off >= 1; off >>= 1) ss += __shfl_xor(ss, off, 64);
        if (lane == 0) scaleS[rl] = rsqrtf(ss / (float)DINNER + 1e-5f);
#pragma unroll
        for (int i2 = 0; i2 < 4; ++i2) {
            int k = i2 * 512 + lane * 8;
            ushort4 u0, u1;
            u0.x = f2bf(gv[i2 * 8 + 0]); u0.y = f2bf(gv[i2 * 8 + 1]);
            u0.z = f2bf(gv[i2 * 8 + 2]); u0.w = f2bf(gv[i2 * 8 + 3]);
            u1.x = f2bf(gv[i2 * 8 + 4]); u1.y = f2bf(gv[i2 * 8 + 5]);
            u1.z = f2bf(gv[i2 * 8 + 6]); u1.w = f2bf(gv[i2 * 8 + 7]);
            *(ushort4*)(&Gs[rl][k]) = u0;
            *(ushort4*)(&Gs[rl][k + 4]) = u1;
        }
    }
    __syncthreads();
    // Rescale: thread handles k-range [tid*8, tid*8+8) for all 16 rows
    {
        int k0 = tid * 8;
        float4 n0 = *(const float4*)(nw + k0);
        float4 n1 = *(const float4*)(nw + k0 + 4);
        float nv[8] = {n0.x, n0.y, n0.z, n0.w, n1.x, n1.y, n1.z, n1.w};
#pragma unroll
        for (int r = 0; r < 16; ++r) {
            float sc = scaleS[r];
            ushort4 a0 = *(const ushort4*)(&Gs[r][k0]);
            ushort4 a1 = *(const ushort4*)(&Gs[r][k0 + 4]);
            ushort4 o0, o1;
            o0.x = f2bf(bf2f(a0.x) * sc * nv[0]); o0.y = f2bf(bf2f(a0.y) * sc * nv[1]);
            o0.z = f2bf(bf2f(a0.z) * sc * nv[2]); o0.w = f2bf(bf2f(a0.w) * sc * nv[3]);
            o1.x = f2bf(bf2f(a1.x) * sc * nv[4]); o1.y = f2bf(bf2f(a1.y) * sc * nv[5]);
            o1.z = f2bf(bf2f(a1.z) * sc * nv[6]); o1.w = f2bf(bf2f(a1.w) * sc * nv[7]);
            *(ushort4*)(&Gs[r][k0]) = o0;
            *(ushort4*)(&Gs[r][k0 + 4]) = o1;
        }
    }
    __syncthreads();
    // Phase B: wave w handles K slice [w*512, w*512+512)
    const int fr = lane & 15, fq = lane >> 4;
    f32x4 acc[3] = {};
    const int kbase = w * 512;
    for (int ks = 0; ks < 16; ++ks) {
        int k0 = kbase + ks * 32;
        bf16x8 a = *(const bf16x8*)(&Gs[fr][k0 + fq * 8]);
#pragma unroll
        for (int nt = 0; nt < 3; ++nt) {
            bf16x8 bb = *(const bf16x8*)(Wt + (size_t)(nt * 16 + fr) * DINNER + k0 + fq * 8);
            acc[nt] = __builtin_amdgcn_mfma_f32_16x16x32_bf16(a, bb, acc[nt], 0, 0, 0);
        }
    }
#pragma unroll
    for (int nt = 0; nt < 3; ++nt)
        *(f32x4*)(&Rs[nt][w][lane * 4]) = acc[nt];
    __syncthreads();
    if (tid < 64) {
#pragma unroll
        for (int nt = 0; nt < 3; ++nt) {
            int col = nt * 16 + (lane & 15);
            float bb = bcls[col];
#pragma unroll
            for (int j = 0; j < 4; ++j) {
                float s = Rs[nt][0][lane * 4 + j] + Rs[nt][1][lane * 4 + j]
                        + Rs[nt][2][lane * 4 + j] + Rs[nt][3][lane * 4 + j];
                int row = m0 + (lane >> 4) * 4 + j;
                out[(size_t)row * NCLS + col] = s + bb;
            }
        }
    }
}

// ---------------- launch -----------------------------------------------------
extern "C" void kernel_launch(void* const* d_in, const int* in_sizes, int n_in,
                              void* d_out, int out_size, void* d_ws, size_t ws_size,
                              hipStream_t stream) {
    const float* inputs  = (const float*)d_in[0];
    const float* W_in    = (const float*)d_in[1];
    const float* conv_w  = (const float*)d_in[2];
    const float* conv_b  = (const float*)d_in[3];
    const float* dt_bias = (const float*)d_in[4];
    const float* A_log   = (const float*)d_in[5];
    const float* Dvec    = (const float*)d_in[6];
    const float* norm_w  = (const float*)d_in[7];
    // d_in[8] = W_out (unused by reference output)
    const float* W_cls   = (const float*)d_in[9];
    const float* b_cls   = (const float*)d_in[10];
    float* out = (float*)d_out;

    // workspace layout
    float* ws = (float*)d_ws;
    unsigned short* zxb = (unsigned short*)ws;                   // BL*4384 bf16
    float* xbc   = ws + (size_t)BL * DINPROJ / 2;                // BL*2304 fp32
    float* dtb   = xbc + (size_t)BL * CONVDIM;                   // BL*32
    float* lam_g = dtb + (size_t)BL * NHEADS;                    // 512
    float* esc_g = lam_g + 512;                                  // 512*64
    unsigned short* yb     = (unsigned short*)(esc_g + 512 * QC);          // BL*2048 bf16
    unsigned short* Sc_bf  = yb + (size_t)BL * DINNER;                     // 512*8192 bf16
    unsigned short* Sin_bf = Sc_bf + (size_t)512 * HEADDIM * DSTATE;       // 512*8192 bf16
    unsigned short* abf    = Sin_bf + (size_t)512 * HEADDIM * DSTATE;      // BL*1024
    unsigned short* wtbf   = abf + (size_t)BL * DMODEL;                    // 4480*1024 (padded)
    unsigned short* wclsbf = wtbf + (size_t)NPROJPAD * DMODEL;             // 48*2048

    k_prep<<<dim3(1024 + 4384 + 48), dim3(256), 0, stream>>>(inputs, abf, W_in, wtbf,
                                                             W_cls, wclsbf);
    k_gemm_in<<<dim3(NPROJPAD / 128, BL / 128), dim3(256), 0, stream>>>(abf, wtbf, zxb);
    k_conv_dt<<<dim3(10, BL), dim3(256), 0, stream>>>(zxb, conv_w, conv_b, dt_bias, xbc, dtb);
    k_chunk<<<dim3(BATCH * NHEADS * NCH), dim3(256), 0, stream>>>(xbc, dtb, A_log, Dvec,
                                                                  yb, Sc_bf, lam_g, esc_g);
    k_chain<<<dim3(BATCH * NHEADS * 4), dim3(256), 0, stream>>>(Sc_bf, lam_g, Sin_bf);
    k_cross<<<dim3(BATCH * NHEADS * NCH), dim3(256), 0, stream>>>(xbc, esc_g, Sin_bf, yb);
    k_gn_cls<<<dim3(BL / 16), dim3(256), 0, stream>>>(zxb, yb, norm_w, wclsbf, b_cls, out);
}

// Round 8
// 171.252 us; speedup vs baseline: 1.0359x; 1.0162x over previous
//
#include <hip/hip_runtime.h>
#include <hip/hip_bf16.h>
#include <cstdint>

// Problem constants
#define BATCH 2
#define SEQLEN 512
#define BL (BATCH*SEQLEN)       // 1024 rows
#define DMODEL 1024
#define DINNER 2048
#define NHEADS 32
#define HEADDIM 64
#define DSTATE 128
#define CONVDIM 2304            // DINNER + 2*DSTATE
#define DINPROJ 4384            // 2*DINNER + 2*DSTATE + NHEADS
#define NPROJPAD 4480           // DINPROJ padded: 28 x 160 exactly (one block wave)
#define NCLS 48
#define QC 64                   // scan chunk length
#define NCH 8                   // chunks per sequence (SEQLEN/QC)

typedef short bf16x8 __attribute__((ext_vector_type(8)));
typedef float f32x4  __attribute__((ext_vector_type(4)));
typedef unsigned int u32;
typedef const __attribute__((address_space(1))) u32 gu32;
typedef __attribute__((address_space(3))) u32 lu32;

static __device__ __forceinline__ void gl16(const void* g, void* l) {
    // async global->LDS DMA, 16B/lane; LDS dest = wave-uniform base + lane*16
    __builtin_amdgcn_global_load_lds((gu32*)g, (lu32*)l, 16, 0, 0);
}

static __device__ __forceinline__ unsigned short f2bf(float f) {
    unsigned u = __float_as_uint(f);
    unsigned r = (u + 0x7FFFu + ((u >> 16) & 1u)) >> 16;
    return (unsigned short)r;
}
static __device__ __forceinline__ float bf2f(unsigned short u) {
    return __uint_as_float(((unsigned)u) << 16);
}

// ---------------- K0: merged prep: cvt_a | transpose W_in | cls W^T ----------
__global__ __launch_bounds__(256) void k_prep(const float* __restrict__ in,
                                              unsigned short* __restrict__ abf,
                                              const float* __restrict__ W,
                                              unsigned short* __restrict__ Wt,
                                              const float* __restrict__ Wcls,
                                              unsigned short* __restrict__ Wtc) {
    __shared__ float tile[32][33];
    int bid = blockIdx.x;
    int tid = threadIdx.x;
    if (bid < 1024) {
        int i = (bid * 256 + tid) * 4;
        float4 v = *(const float4*)(in + i);
        ushort4 o;
        o.x = f2bf(v.x); o.y = f2bf(v.y); o.z = f2bf(v.z); o.w = f2bf(v.w);
        *(ushort4*)(abf + i) = o;
    } else if (bid < 1024 + 4384) {
        int t = bid - 1024;
        int n0 = (t % 137) * 32;      // over 4384
        int k0 = (t / 137) * 32;      // over 1024
        int tx = tid & 31, ty = tid >> 5;
#pragma unroll
        for (int i = 0; i < 4; ++i) {
            int k = k0 + ty + i * 8;
            tile[ty + i * 8][tx] = W[(size_t)k * DINPROJ + n0 + tx];
        }
        __syncthreads();
#pragma unroll
        for (int i = 0; i < 4; ++i) {
            int n = n0 + ty + i * 8;
            Wt[(size_t)n * DMODEL + k0 + tx] = f2bf(tile[tx][ty + i * 8]);
        }
    } else {
        int n = bid - (1024 + 4384);   // 0..47
        for (int k = tid; k < DINNER; k += 256)
            Wtc[(size_t)n * DINNER + k] = f2bf(Wcls[(size_t)k * NCLS + n]);
    }
}

// ---------------- K1: zxbcdt = A(1024x1024) @ W(1024x4384) -> bf16 -----------
// BM=128, BN=160, BK=64 (two 32-halves); grid 28x8 = 224 blocks = ONE pass
// over 256 CUs (no dispatch tail). 4 waves 2x2; 40 MFMA + ~9 gl16/wave/iter.
__global__ __launch_bounds__(256) void k_gemm_in(const unsigned short* __restrict__ A,
                                                 const unsigned short* __restrict__ Bt,
                                                 unsigned short* __restrict__ C) {
    __shared__ unsigned short As[2 * 4096];   // [half][128][32] unpadded (DMA layout)
    __shared__ unsigned short Bs[2 * 5120];   // [half][160][32]
    const int tid  = threadIdx.x;
    const int m0   = blockIdx.y * 128;
    const int n0   = blockIdx.x * 160;
    const int w    = tid >> 6;
    const int lane = tid & 63;
    const int wm   = w >> 1, wn = w & 1;
    const int fr   = lane & 15, fq = lane >> 4;
    const int lrow = lane >> 2;           // 0..15
    const int skg  = (lane & 3) * 8;      // k-offset in ushorts within a 32-half
    const unsigned short* gA0 = A + (size_t)(m0 + w * 16 + lrow) * DMODEL + skg;
    const unsigned short* gA1 = gA0 + (size_t)64 * DMODEL;

    f32x4 acc[4][5] = {};
    for (int k0 = 0; k0 < DMODEL; k0 += 64) {
        __syncthreads();
#pragma unroll
        for (int hh = 0; hh < 2; ++hh) {
            int kg = k0 + hh * 32;
            gl16(gA0 + kg, As + hh * 4096 + w * 512);
            gl16(gA1 + kg, As + hh * 4096 + 2048 + w * 512);
            // B: 160 rows x 32 ushorts = 10 x 1KB wave-ops; wave w takes o = w, w+4, w+8
            for (int o = w; o < 10; o += 4) {
                const unsigned short* gB = Bt + (size_t)(n0 + o * 16 + lrow) * DMODEL + skg + kg;
                gl16(gB, Bs + hh * 5120 + o * 512);
            }
        }
        __syncthreads();
#pragma unroll
        for (int hh = 0; hh < 2; ++hh) {
            bf16x8 af[4], bfr[5];
#pragma unroll
            for (int mt = 0; mt < 4; ++mt)
                af[mt] = *(const bf16x8*)(&As[hh * 4096 + (wm * 64 + mt * 16 + fr) * 32 + fq * 8]);
#pragma unroll
            for (int nt = 0; nt < 5; ++nt)
                bfr[nt] = *(const bf16x8*)(&Bs[hh * 5120 + (wn * 80 + nt * 16 + fr) * 32 + fq * 8]);
#pragma unroll
            for (int mt = 0; mt < 4; ++mt)
#pragma unroll
                for (int nt = 0; nt < 5; ++nt)
                    acc[mt][nt] = __builtin_amdgcn_mfma_f32_16x16x32_bf16(af[mt], bfr[nt], acc[mt][nt], 0, 0, 0);
        }
    }
#pragma unroll
    for (int mt = 0; mt < 4; ++mt) {
#pragma unroll
        for (int nt = 0; nt < 5; ++nt) {
            int col = n0 + wn * 80 + nt * 16 + fr;
            if (col < DINPROJ) {
#pragma unroll
                for (int r = 0; r < 4; ++r) {
                    int row = m0 + wm * 64 + mt * 16 + fq * 4 + r;
                    C[(size_t)row * DINPROJ + col] = f2bf(acc[mt][nt][r]);
                }
            }
        }
    }
}

// ---------------- K2: causal depthwise conv + silu, and dt (bf16 zx) ---------
__global__ __launch_bounds__(256) void k_conv_dt(const unsigned short* __restrict__ zx,
                                                 const float* __restrict__ conv_w,
                                                 const float* __restrict__ conv_b,
                                                 const float* __restrict__ dt_bias,
                                                 float* __restrict__ xbc,
                                                 float* __restrict__ dtb) {
    int row = blockIdx.y;                 // b*512 + l
    int c   = blockIdx.x * 256 + threadIdx.x;
    int b = row >> 9, l = row & 511;
    if (c < CONVDIM) {
        float acc = conv_b[c];
#pragma unroll
        for (int j = 0; j < 4; ++j) {
            int ls = l - 3 + j;
            float v = (ls >= 0) ? bf2f(zx[((size_t)(b * SEQLEN + ls)) * DINPROJ + DINNER + c]) : 0.f;
            acc += v * conv_w[c * 4 + j];
        }
        float s = acc / (1.f + expf(-acc));
        xbc[(size_t)row * CONVDIM + c] = s;
    } else if (c < CONVDIM + NHEADS) {
        int h = c - CONVDIM;
        float raw = bf2f(zx[(size_t)row * DINPROJ + (DINNER + CONVDIM) + h]) + dt_bias[h];
        float dt = (raw > 20.f) ? raw : log1pf(expf(raw));
        dtb[row * NHEADS + h] = dt;
    }
}

// ---------------- K3a: chunked SSD, intra-chunk (Y_intra bf16 + Sc bf16) -----
__global__ __launch_bounds__(256) void k_chunk(const float* __restrict__ xbc,
                                               const float* __restrict__ dtb,
                                               const float* __restrict__ A_log,
                                               const float* __restrict__ Dvec,
                                               unsigned short* __restrict__ yb,
                                               unsigned short* __restrict__ Sc_bf,
                                               float* __restrict__ lam_g,
                                               float* __restrict__ esc_g) {
    const int gid = blockIdx.x;           // 0..511
    const int cq = gid & 7;
    const int h = (gid >> 3) & 31;
    const int b = gid >> 8;
    const int row0 = b * SEQLEN + cq * QC;

    __shared__ float cumS[QC], wS[QC], dtS[QC];
    __shared__ unsigned short Xt[QC][72];        // [p][s]
    __shared__ unsigned short Bs[QC][136];       // [s][n]
    __shared__ unsigned short BtW[DSTATE][72];   // [n][s], weighted by w[s]
    __shared__ unsigned short Cs[QC][136];       // [t][n]
    __shared__ unsigned short Gs[QC][72];        // [t][s], masked+decayed

    const int tid = threadIdx.x;
    if (tid < 64) {
        float dtv = dtb[(size_t)(row0 + tid) * NHEADS + h];
        float nA = -expf(A_log[h]);
        float x = dtv * nA;
#pragma unroll
        for (int off = 1; off < 64; off <<= 1) {
            float v = __shfl_up(x, off, 64);
            if (tid >= off) x += v;
        }
        float cumTot = __shfl(x, 63, 64);
        cumS[tid] = x;
        dtS[tid] = dtv;
        wS[tid] = expf(cumTot - x) * dtv;
        esc_g[(size_t)gid * QC + tid] = expf(x);
        if (tid == 0) lam_g[gid] = expf(cumTot);
    }
    __syncthreads();

    {
        int row = tid >> 2;       // s / t index 0..63
        int g = tid & 3;
        const float* rp = xbc + (size_t)(row0 + row) * CONVDIM;
        float wrow = wS[row];
#pragma unroll
        for (int i = 0; i < 4; ++i) {
            float4 v = *(const float4*)(rp + h * HEADDIM + g * 16 + i * 4);
            int p = g * 16 + i * 4;
            Xt[p + 0][row] = f2bf(v.x);
            Xt[p + 1][row] = f2bf(v.y);
            Xt[p + 2][row] = f2bf(v.z);
            Xt[p + 3][row] = f2bf(v.w);
        }
#pragma unroll
        for (int i = 0; i < 8; ++i) {
            int n = g * 32 + i * 4;
            float4 v = *(const float4*)(rp + DINNER + n);
            ushort4 u;
            u.x = f2bf(v.x); u.y = f2bf(v.y); u.z = f2bf(v.z); u.w = f2bf(v.w);
            *(ushort4*)(&Bs[row][n]) = u;
            BtW[n + 0][row] = f2bf(v.x * wrow);
            BtW[n + 1][row] = f2bf(v.y * wrow);
            BtW[n + 2][row] = f2bf(v.z * wrow);
            BtW[n + 3][row] = f2bf(v.w * wrow);
        }
#pragma unroll
        for (int i = 0; i < 8; ++i) {
            int n = g * 32 + i * 4;
            float4 v = *(const float4*)(rp + DINNER + DSTATE + n);
            ushort4 u;
            u.x = f2bf(v.x); u.y = f2bf(v.y); u.z = f2bf(v.z); u.w = f2bf(v.w);
            *(ushort4*)(&Cs[row][n]) = u;
        }
    }
    __syncthreads();

    const int w = tid >> 6, lane = tid & 63;
    const int fr = lane & 15, fq = lane >> 4, fk = (lane >> 4) * 8;

    f32x4 accG[4] = {};
#pragma unroll
    for (int kk = 0; kk < 4; ++kk) {
        bf16x8 a = *(const bf16x8*)(&Cs[w * 16 + fr][kk * 32 + fk]);
#pragma unroll
        for (int nt = 0; nt < 4; ++nt) {
            bf16x8 bb = *(const bf16x8*)(&Bs[nt * 16 + fr][kk * 32 + fk]);
            accG[nt] = __builtin_amdgcn_mfma_f32_16x16x32_bf16(a, bb, accG[nt], 0, 0, 0);
        }
    }
#pragma unroll
    for (int nt = 0; nt < 4; ++nt) {
        int s = nt * 16 + fr;
        float cs = cumS[s], dts = dtS[s];
#pragma unroll
        for (int r = 0; r < 4; ++r) {
            int t = w * 16 + fq * 4 + r;
            float val = (s <= t) ? accG[nt][r] * expf(cumS[t] - cs) * dts : 0.f;
            Gs[t][s] = f2bf(val);
        }
    }
    __syncthreads();

    f32x4 accY[4] = {};
#pragma unroll
    for (int kk = 0; kk < 2; ++kk) {
        bf16x8 a = *(const bf16x8*)(&Gs[w * 16 + fr][kk * 32 + fk]);
#pragma unroll
        for (int pt = 0; pt < 4; ++pt) {
            bf16x8 bb = *(const bf16x8*)(&Xt[pt * 16 + fr][kk * 32 + fk]);
            accY[pt] = __builtin_amdgcn_mfma_f32_16x16x32_bf16(a, bb, accY[pt], 0, 0, 0);
        }
    }
    f32x4 accS[8] = {};
#pragma unroll
    for (int kk = 0; kk < 2; ++kk) {
        bf16x8 a = *(const bf16x8*)(&Xt[w * 16 + fr][kk * 32 + fk]);
#pragma unroll
        for (int nt = 0; nt < 8; ++nt) {
            bf16x8 bb = *(const bf16x8*)(&BtW[nt * 16 + fr][kk * 32 + fk]);
            accS[nt] = __builtin_amdgcn_mfma_f32_16x16x32_bf16(a, bb, accS[nt], 0, 0, 0);
        }
    }
    float Dh = Dvec[h];
#pragma unroll
    for (int pt = 0; pt < 4; ++pt) {
        int p = pt * 16 + fr;
#pragma unroll
        for (int r = 0; r < 4; ++r) {
            int t = w * 16 + fq * 4 + r;
            float xv = bf2f(Xt[p][t]);   // x already staged in LDS (bf16)
            yb[(size_t)(row0 + t) * DINNER + h * HEADDIM + p] = f2bf(accY[pt][r] + Dh * xv);
        }
    }
    unsigned short* scp = Sc_bf + (size_t)gid * (HEADDIM * DSTATE);
#pragma unroll
    for (int nt = 0; nt < 8; ++nt) {
        int n = nt * 16 + fr;
#pragma unroll
        for (int r = 0; r < 4; ++r) {
            int p = w * 16 + fq * 4 + r;
            scp[p * DSTATE + n] = f2bf(accS[nt][r]);
        }
    }
}

// ---------------- K3b: inter-chunk state chain (256 WGs, serial over 8) ------
__global__ __launch_bounds__(256) void k_chain(const unsigned short* __restrict__ Sc_bf,
                                               const float* __restrict__ lam_g,
                                               unsigned short* __restrict__ Sin_bf) {
    int bh = blockIdx.x >> 2;      // 0..63
    int sl = blockIdx.x & 3;       // slice of the 8192-elem state
    int tid = threadIdx.x;
    float s[8];
#pragma unroll
    for (int i = 0; i < 8; ++i) s[i] = 0.f;
    for (int c = 0; c < NCH; ++c) {
        size_t base = (size_t)(bh * NCH + c) * (HEADDIM * DSTATE) + sl * 2048 + tid * 8;
        ushort4 o0, o1;
        o0.x = f2bf(s[0]); o0.y = f2bf(s[1]); o0.z = f2bf(s[2]); o0.w = f2bf(s[3]);
        o1.x = f2bf(s[4]); o1.y = f2bf(s[5]); o1.z = f2bf(s[6]); o1.w = f2bf(s[7]);
        *(ushort4*)(Sin_bf + base) = o0;
        *(ushort4*)(Sin_bf + base + 4) = o1;
        float lam = lam_g[bh * NCH + c];
        ushort4 v0 = *(const ushort4*)(Sc_bf + base);
        ushort4 v1 = *(const ushort4*)(Sc_bf + base + 4);
        s[0] = s[0] * lam + bf2f(v0.x);
        s[1] = s[1] * lam + bf2f(v0.y);
        s[2] = s[2] * lam + bf2f(v0.z);
        s[3] = s[3] * lam + bf2f(v0.w);
        s[4] = s[4] * lam + bf2f(v1.x);
        s[5] = s[5] * lam + bf2f(v1.y);
        s[6] = s[6] * lam + bf2f(v1.z);
        s[7] = s[7] * lam + bf2f(v1.w);
    }
}

// ---------------- K3c: cross-chunk: Y += exp(cum[t]) * C_t · S_in (bf16 yb) --
__global__ __launch_bounds__(256) void k_cross(const float* __restrict__ xbc,
                                               const float* __restrict__ esc_g,
                                               const unsigned short* __restrict__ Sin_bf,
                                               unsigned short* __restrict__ yb) {
    const int gid = blockIdx.x;
    const int cq = gid & 7;
    const int h = (gid >> 3) & 31;
    const int b = gid >> 8;
    const int row0 = b * SEQLEN + cq * QC;
    __shared__ unsigned short Ct[QC][136];   // [t][n], scaled by esc[t]
    __shared__ unsigned short Ss[QC][136];   // [p][n]
    const int tid = threadIdx.x;
    {
        int row = tid >> 2, g = tid & 3;
        const float* rp = xbc + (size_t)(row0 + row) * CONVDIM + DINNER + DSTATE;
        float esc = esc_g[(size_t)gid * QC + row];
#pragma unroll
        for (int i = 0; i < 8; ++i) {
            int n = g * 32 + i * 4;
            float4 v = *(const float4*)(rp + n);
            ushort4 u;
            u.x = f2bf(v.x * esc); u.y = f2bf(v.y * esc);
            u.z = f2bf(v.z * esc); u.w = f2bf(v.w * esc);
            *(ushort4*)(&Ct[row][n]) = u;
        }
        const uint4* sp = (const uint4*)(Sin_bf + (size_t)gid * (HEADDIM * DSTATE));
#pragma unroll
        for (int i = 0; i < 4; ++i) {
            uint4 v = sp[row * 16 + g * 4 + i];
            *(uint4*)(&Ss[row][g * 32 + i * 8]) = v;
        }
    }
    __syncthreads();
    const int w = tid >> 6, lane = tid & 63;
    const int fr = lane & 15, fq = lane >> 4, fk = (lane >> 4) * 8;
    f32x4 acc[4] = {};
#pragma unroll
    for (int kk = 0; kk < 4; ++kk) {
        bf16x8 a = *(const bf16x8*)(&Ct[w * 16 + fr][kk * 32 + fk]);
#pragma unroll
        for (int pt = 0; pt < 4; ++pt) {
            bf16x8 bb = *(const bf16x8*)(&Ss[pt * 16 + fr][kk * 32 + fk]);
            acc[pt] = __builtin_amdgcn_mfma_f32_16x16x32_bf16(a, bb, acc[pt], 0, 0, 0);
        }
    }
    // disjoint (b,h,chunk) tiles -> plain RMW on bf16 yb is race-free
#pragma unroll
    for (int pt = 0; pt < 4; ++pt) {
        int p = pt * 16 + fr;
#pragma unroll
        for (int r = 0; r < 4; ++r) {
            int t = w * 16 + fq * 4 + r;
            size_t yi = (size_t)(row0 + t) * DINNER + h * HEADDIM + p;
            yb[yi] = f2bf(bf2f(yb[yi]) + acc[pt][r]);
        }
    }
}

// ---------------- K4: fused gated RMSNorm + classifier -----------------------
__global__ __launch_bounds__(256) void k_gn_cls(const unsigned short* __restrict__ zx,
                                                const unsigned short* __restrict__ yb,
                                                const float* __restrict__ nw,
                                                const unsigned short* __restrict__ Wt,
                                                const float* __restrict__ bcls,
                                                float* __restrict__ out) {
    __shared__ unsigned short Gs[16][2048];
    __shared__ float scaleS[16];
    __shared__ float Rs[3][4][256];
    const int m0 = blockIdx.x * 16;
    const int tid = threadIdx.x;
    const int w = tid >> 6, lane = tid & 63;

    // Phase A: wave w -> rows w*4 .. w*4+4
#pragma unroll
    for (int i = 0; i < 4; ++i) {
        int rl = w * 4 + i;
        int row = m0 + rl;
        const unsigned short* yr = yb + (size_t)row * DINNER;
        const unsigned short* zr = zx + (size_t)row * DINPROJ;
        float gv[32];
        float ss = 0.f;
#pragma unroll
        for (int i2 = 0; i2 < 4; ++i2) {
            int k = i2 * 512 + lane * 8;
            ushort4 ya = *(const ushort4*)(yr + k);
            ushort4 ybq = *(const ushort4*)(yr + k + 4);
            ushort4 za = *(const ushort4*)(zr + k);
            ushort4 zbq = *(const ushort4*)(zr + k + 4);
            float ys[8] = {bf2f(ya.x), bf2f(ya.y), bf2f(ya.z), bf2f(ya.w),
                           bf2f(ybq.x), bf2f(ybq.y), bf2f(ybq.z), bf2f(ybq.w)};
            float zs[8] = {bf2f(za.x), bf2f(za.y), bf2f(za.z), bf2f(za.w),
                           bf2f(zbq.x), bf2f(zbq.y), bf2f(zbq.z), bf2f(zbq.w)};
#pragma unroll
            for (int j = 0; j < 8; ++j) {
                float sil = zs[j] / (1.f + expf(-zs[j]));
                float gg = ys[j] * sil;
                gv[i2 * 8 + j] = gg;
                ss += gg * gg;
            }
        }
#pragma unroll
        for (int off = 32; off >= 1; off >>= 1) ss += __shfl_xor(ss, off, 64);
        if (lane == 0) scaleS[rl] = rsqrtf(ss / (float)DINNER + 1e-5f);
#pragma unroll
        for (int i2 = 0; i2 < 4; ++i2) {
            int k = i2 * 512 + lane * 8;
            ushort4 u0, u1;
            u0.x = f2bf(gv[i2 * 8 + 0]); u0.y = f2bf(gv[i2 * 8 + 1]);
            u0.z = f2bf(gv[i2 * 8 + 2]); u0.w = f2bf(gv[i2 * 8 + 3]);
            u1.x = f2bf(gv[i2 * 8 + 4]); u1.y = f2bf(gv[i2 * 8 + 5]);
            u1.z = f2bf(gv[i2 * 8 + 6]); u1.w = f2bf(gv[i2 * 8 + 7]);
            *(ushort4*)(&Gs[rl][k]) = u0;
            *(ushort4*)(&Gs[rl][k + 4]) = u1;
        }
    }
    __syncthreads();
    // Rescale: thread handles k-range [tid*8, tid*8+8) for all 16 rows
    {
        int k0 = tid * 8;
        float4 n0 = *(const float4*)(nw + k0);
        float4 n1 = *(const float4*)(nw + k0 + 4);
        float nv[8] = {n0.x, n0.y, n0.z, n0.w, n1.x, n1.y, n1.z, n1.w};
#pragma unroll
        for (int r = 0; r < 16; ++r) {
            float sc = scaleS[r];
            ushort4 a0 = *(const ushort4*)(&Gs[r][k0]);
            ushort4 a1 = *(const ushort4*)(&Gs[r][k0 + 4]);
            ushort4 o0, o1;
            o0.x = f2bf(bf2f(a0.x) * sc * nv[0]); o0.y = f2bf(bf2f(a0.y) * sc * nv[1]);
            o0.z = f2bf(bf2f(a0.z) * sc * nv[2]); o0.w = f2bf(bf2f(a0.w) * sc * nv[3]);
            o1.x = f2bf(bf2f(a1.x) * sc * nv[4]); o1.y = f2bf(bf2f(a1.y) * sc * nv[5]);
            o1.z = f2bf(bf2f(a1.z) * sc * nv[6]); o1.w = f2bf(bf2f(a1.w) * sc * nv[7]);
            *(ushort4*)(&Gs[r][k0]) = o0;
            *(ushort4*)(&Gs[r][k0 + 4]) = o1;
        }
    }
    __syncthreads();
    // Phase B: wave w handles K slice [w*512, w*512+512)
    const int fr = lane & 15, fq = lane >> 4;
    f32x4 acc[3] = {};
    const int kbase = w * 512;
    for (int ks = 0; ks < 16; ++ks) {
        int k0 = kbase + ks * 32;
        bf16x8 a = *(const bf16x8*)(&Gs[fr][k0 + fq * 8]);
#pragma unroll
        for (int nt = 0; nt < 3; ++nt) {
            bf16x8 bb = *(const bf16x8*)(Wt + (size_t)(nt * 16 + fr) * DINNER + k0 + fq * 8);
            acc[nt] = __builtin_amdgcn_mfma_f32_16x16x32_bf16(a, bb, acc[nt], 0, 0, 0);
        }
    }
#pragma unroll
    for (int nt = 0; nt < 3; ++nt)
        *(f32x4*)(&Rs[nt][w][lane * 4]) = acc[nt];
    __syncthreads();
    if (tid < 64) {
#pragma unroll
        for (int nt = 0; nt < 3; ++nt) {
            int col = nt * 16 + (lane & 15);
            float bb = bcls[col];
#pragma unroll
            for (int j = 0; j < 4; ++j) {
                float s = Rs[nt][0][lane * 4 + j] + Rs[nt][1][lane * 4 + j]
                        + Rs[nt][2][lane * 4 + j] + Rs[nt][3][lane * 4 + j];
                int row = m0 + (lane >> 4) * 4 + j;
                out[(size_t)row * NCLS + col] = s + bb;
            }
        }
    }
}

// ---------------- launch -----------------------------------------------------
extern "C" void kernel_launch(void* const* d_in, const int* in_sizes, int n_in,
                              void* d_out, int out_size, void* d_ws, size_t ws_size,
                              hipStream_t stream) {
    const float* inputs  = (const float*)d_in[0];
    const float* W_in    = (const float*)d_in[1];
    const float* conv_w  = (const float*)d_in[2];
    const float* conv_b  = (const float*)d_in[3];
    const float* dt_bias = (const float*)d_in[4];
    const float* A_log   = (const float*)d_in[5];
    const float* Dvec    = (const float*)d_in[6];
    const float* norm_w  = (const float*)d_in[7];
    // d_in[8] = W_out (unused by reference output)
    const float* W_cls   = (const float*)d_in[9];
    const float* b_cls   = (const float*)d_in[10];
    float* out = (float*)d_out;

    // workspace layout
    float* ws = (float*)d_ws;
    unsigned short* zxb = (unsigned short*)ws;                   // BL*4384 bf16
    float* xbc   = ws + (size_t)BL * DINPROJ / 2;                // BL*2304 fp32
    float* dtb   = xbc + (size_t)BL * CONVDIM;                   // BL*32
    float* lam_g = dtb + (size_t)BL * NHEADS;                    // 512
    float* esc_g = lam_g + 512;                                  // 512*64
    unsigned short* yb     = (unsigned short*)(esc_g + 512 * QC);          // BL*2048 bf16
    unsigned short* Sc_bf  = yb + (size_t)BL * DINNER;                     // 512*8192 bf16
    unsigned short* Sin_bf = Sc_bf + (size_t)512 * HEADDIM * DSTATE;       // 512*8192 bf16
    unsigned short* abf    = Sin_bf + (size_t)512 * HEADDIM * DSTATE;      // BL*1024
    unsigned short* wtbf   = abf + (size_t)BL * DMODEL;                    // 4480*1024 (padded)
    unsigned short* wclsbf = wtbf + (size_t)NPROJPAD * DMODEL;             // 48*2048

    k_prep<<<dim3(1024 + 4384 + 48), dim3(256), 0, stream>>>(inputs, abf, W_in, wtbf,
                                                             W_cls, wclsbf);
    k_gemm_in<<<dim3(NPROJPAD / 160, BL / 128), dim3(256), 0, stream>>>(abf, wtbf, zxb);
    k_conv_dt<<<dim3(10, BL), dim3(256), 0, stream>>>(zxb, conv_w, conv_b, dt_bias, xbc, dtb);
    k_chunk<<<dim3(BATCH * NHEADS * NCH), dim3(256), 0, stream>>>(xbc, dtb, A_log, Dvec,
                                                                  yb, Sc_bf, lam_g, esc_g);
    k_chain<<<dim3(BATCH * NHEADS * 4), dim3(256), 0, stream>>>(Sc_bf, lam_g, Sin_bf);
    k_cross<<<dim3(BATCH * NHEADS * NCH), dim3(256), 0, stream>>>(xbc, esc_g, Sin_bf, yb);
    k_gn_cls<<<dim3(BL / 16), dim3(256), 0, stream>>>(zxb, yb, norm_w, wclsbf, b_cls, out);
}